// Round 3
// baseline (570.319 us; speedup 1.0000x reference)
//
#include <hip/hip_runtime.h>

// Model_65678639890860 R3: chain-shortened 24-lane LSTM recurrence.
// Lane = v*4+u owns all 4 gates of (v,u). Serial cycle per step:
//   h --dpp bc--> y-tree(3 fma) -> exp2 -> fma -> rcp = r
//     -> a=fma(cx,r,hdot) -> exp2 -> add -> mul(-d_i*d_g) -> rcp
//     -> c'=fma -> exp2 -> add -> mul -> rcp = h
// Algebra folds: all gate weights scaled by -log2e; c carried as c' = -L2E*c
// via s=sqrt(1/L2E) absorbed into i/g biases; x carried as r = w2_direct*ry
// (direct gate = per-lane argmax |w2|), so each gate arg is ONE fma off r;
// wx and bl constants folded into biases; tanh materialized only at the end.

#define L2E 1.4426950408889634f

__device__ __forceinline__ float rcp_f(float x) { return __builtin_amdgcn_rcpf(x); }
__device__ __forceinline__ float exp2_f(float x) { return __builtin_amdgcn_exp2f(x); }

template <int CTRL>
__device__ __forceinline__ float dpp_f(float x) {
    return __int_as_float(
        __builtin_amdgcn_mov_dpp(__float_as_int(x), CTRL, 0xF, 0xF, true));
}

__global__ __launch_bounds__(64) void lstm_seq(
    const float* __restrict__ vel, const float* __restrict__ h0,
    const float* __restrict__ c0,
    const float* __restrict__ Wix, const float* __restrict__ Wih, const float* __restrict__ bi,
    const float* __restrict__ Wfx, const float* __restrict__ Wfh, const float* __restrict__ bf,
    const float* __restrict__ Wox, const float* __restrict__ Woh, const float* __restrict__ bo,
    const float* __restrict__ Wgx, const float* __restrict__ Wgh, const float* __restrict__ bg,
    const float* __restrict__ linear, const float* __restrict__ bl,
    const int* __restrict__ seqlen, float* __restrict__ out)
{
    const int lane = threadIdx.x;
    const int l = lane < 24 ? lane : 23;     // junk lanes mirror lane 23 (bounded)
    const int v = l >> 2;
    const int u = l & 3;

    const float s  = 0.83255461115769776f;   // sqrt(1/log2 e)
    const float cs = -0.26449287164720088f;  // log2(s)

    // gate order: 0=i, 1=f, 2=o, 3=g
    const float* Wh[4] = {Wih, Wfh, Woh, Wgh};
    const float* Wx[4] = {Wix, Wfx, Wox, Wgx};
    const float* Bb[4] = {bi,  bf,  bo,  bg};

    float wh[4][4], bb[4], w2[4];
#pragma unroll
    for (int g = 0; g < 4; ++g) {
#pragma unroll
        for (int k = 0; k < 4; ++k) wh[g][k] = -L2E * Wh[g][l * 4 + k];
        const float wxp = -L2E * Wx[g][u * 6 + v];
        bb[g] = -L2E * Bb[g][l] + wxp;       // bias + wx fold (x-constant part)
        w2[g] = -2.0f * wxp;
        if (g == 0 || g == 3) bb[g] += cs;   // s-fold for i and g gates
    }

    // direct gate = argmax |w2| (numerical safety: |cx| <= 1)
    float w2d = w2[0];
#pragma unroll
    for (int g = 1; g < 4; ++g) if (fabsf(w2[g]) > fabsf(w2d)) w2d = w2[g];
    const float kk  = 1.0f / w2d;
    float cx[4];
#pragma unroll
    for (int g = 0; g < 4; ++g) cx[g] = w2[g] * kk;
    const float sgn = (kk < 0.0f) ? -1.0f : 1.0f;
    const float cl  = log2f(fabsf(kk));

    float lp[4];
#pragma unroll
    for (int k = 0; k < 4; ++k) lp[k] = 2.0f * L2E * linear[v * 4 + k];
    const float Ky = 2.0f * L2E * bl[v] + cl;
    const float cout = -2.0f * kk;

    // state: hb0..3 (quad h row), r (scaled x-recip), cp (= -L2E * c)
    float hb0 = h0[v * 4 + 0], hb1 = h0[v * 4 + 1];
    float hb2 = h0[v * 4 + 2], hb3 = h0[v * 4 + 3];
    float cp = -L2E * c0[l];
    float r  = w2d * (0.5f * (1.0f - vel[v]));   // so cx[g]*r = w2[g]*ry0, x0=vel
    const int T = seqlen[0];

#pragma unroll 2
    for (int t = 0; t < T; ++t) {
        // hdots (off critical chain: ready before r)
        float hd0 = fmaf(wh[0][0], hb0, fmaf(wh[0][1], hb1, fmaf(wh[0][2], hb2, fmaf(wh[0][3], hb3, bb[0]))));
        float hd1 = fmaf(wh[1][0], hb0, fmaf(wh[1][1], hb1, fmaf(wh[1][2], hb2, fmaf(wh[1][3], hb3, bb[1]))));
        float hd2 = fmaf(wh[2][0], hb0, fmaf(wh[2][1], hb1, fmaf(wh[2][2], hb2, fmaf(wh[2][3], hb3, bb[2]))));
        float hd3 = fmaf(wh[3][0], hb0, fmaf(wh[3][1], hb1, fmaf(wh[3][2], hb2, fmaf(wh[3][3], hb3, bb[3]))));

        // gate args: one fma off the carried r
        const float a0 = fmaf(cx[0], r, hd0);
        const float a1 = fmaf(cx[1], r, hd1);
        const float a2 = fmaf(cx[2], r, hd2);
        const float a3 = fmaf(cx[3], r, hd3);

        const float e0 = exp2_f(a0);
        const float e3 = exp2_f(a3);
        const float e1 = exp2_f(a1);
        const float e2 = exp2_f(a2);

        const float d0 = s + e0;            // s*(1+e_i)  (cs folded into bias)
        const float d3 = s + e3;            // s*(1+e_g)
        const float d1 = 1.0f + e1;         // 1+e_f
        const float d2 = 1.0f + e2;         // 1+e_o

        const float igp = rcp_f(-d0 * d3);  // = -L2E * sig(i)*sig(g)
        const float ft  = rcp_f(d1);

        cp = fmaf(ft, cp, igp);             // c' = f*c' - L2E*i*g

        const float dc = 1.0f + exp2_f(cp); // 1 + e^{-c}
        const float h  = rcp_f(d2 * dc);    // sig(o)*sig(c)

        // broadcast new h across quad
        hb0 = dpp_f<0x00>(h);
        hb1 = dpp_f<0x55>(h);
        hb2 = dpp_f<0xAA>(h);
        hb3 = dpp_f<0xFF>(h);

        // next x (as scaled recip): r = rcp(kk*(1+2^m)), m = 2L2E*(lin.h+bl)
        const float p  = fmaf(lp[1], hb1, fmaf(lp[0], hb0, Ky));
        const float q  = fmaf(lp[3], hb3, lp[2] * hb2);
        const float ey = exp2_f(p + q);     // 2^{m + log2|kk|}
        r = rcp_f(fmaf(sgn, ey, kk));       // = w2d * 1/(1+2^m)
    }

    if (lane < 24 && u == 0) out[v] = fmaf(cout, r, 1.0f);  // tanh(y_last)
}

extern "C" void kernel_launch(void* const* d_in, const int* in_sizes, int n_in,
                              void* d_out, int out_size, void* d_ws, size_t ws_size,
                              hipStream_t stream) {
    (void)in_sizes; (void)n_in; (void)out_size; (void)d_ws; (void)ws_size;
    lstm_seq<<<1, 64, 0, stream>>>(
        (const float*)d_in[0],  (const float*)d_in[1],  (const float*)d_in[2],
        (const float*)d_in[3],  (const float*)d_in[4],  (const float*)d_in[5],
        (const float*)d_in[6],  (const float*)d_in[7],  (const float*)d_in[8],
        (const float*)d_in[9],  (const float*)d_in[10], (const float*)d_in[11],
        (const float*)d_in[12], (const float*)d_in[13], (const float*)d_in[14],
        (const float*)d_in[15], (const float*)d_in[16],
        (const int*)d_in[17],   (float*)d_out);
}